// Round 12
// baseline (84.219 us; speedup 1.0000x reference)
//
#include <hip/hip_runtime.h>

#define IC 128
#define OC 256
#define RR 64
#define CCOLS 64
#define HO 62
#define WO 62
#define NB 16

// Fragment-major dense bf16 weights:
//   W9Tf[chunk][g][lane][elem], chunk = kp*8+ck (72), g = oc>>5 (8 groups),
//   lane = (oc&31) + 32*khalf (64), elem = c&7 (8 bf16 = 16 B).
// A wave's A-fragment load for one chunk/group is base + lane*16: 1 KB
// contiguous (coalesced; the R8 win).
#define W9T_BYTES (9 * OC * IC * 2)   // 589824
#define CHUNK_STRIDE 8192             // 8 ocgroups * 64 lanes * 16 B
#define LDSROW 16384                  // one image row: 64 x * 256 B

typedef __bf16 bf16x8 __attribute__((ext_vector_type(8)));
typedef float f32x16 __attribute__((ext_vector_type(16)));

__device__ __forceinline__ unsigned short f2bf(float f) {
    unsigned u = __builtin_bit_cast(unsigned, f);
    u += 0x7FFFu + ((u >> 16) & 1u);   // round-to-nearest-even
    return (unsigned short)(u >> 16);
}

__global__ void prep_weights(const float* __restrict__ wv,
                             const int* __restrict__ iwi,
                             const int* __restrict__ flen,
                             const int* __restrict__ sp,
                             unsigned char* __restrict__ W9Tf) {
    const int oc = blockIdx.x;
    const int s = sp[oc];
    const int n = flen[oc];
    const int g = oc >> 5;
    for (int t = threadIdx.x; t < n; t += blockDim.x) {
        const int ix = iwi[s + t];          // c*4096 + ky*64 + kx
        const int c = ix >> 12;
        const int rem = ix & 4095;
        const int ky = rem >> 6, kx = rem & 63;
        const int kp = ky * 3 + kx;
        const int ck = c >> 4;
        const int khalf = (c >> 3) & 1;
        const int lane = (oc & 31) + (khalf << 5);
        const size_t off = (size_t)(kp * 8 + ck) * CHUNK_STRIDE +
                           g * 1024 + lane * 16 + (c & 7) * 2;
        *(unsigned short*)(W9Tf + off) = f2bf(wv[s + t]);
    }
}

__global__ void bias_kernel(const int* __restrict__ bias_index,
                            const float* __restrict__ bias_value,
                            float* __restrict__ bias_dense, int nbias) {
    int t = threadIdx.x;
    if (t < OC) bias_dense[t] = 0.f;
    __syncthreads();
    if (t < nbias) atomicAdd(&bias_dense[bias_index[t]], bias_value[t]);
}

// Block = (b, 2 output rows) x all 256 oc. 256 threads = 4 waves.
// Wave w: 64 oc (groups 2w, 2w+1) x 64 x (2 n-tiles) x 2 y-rows:
// per K-chunk iteration = 2 coalesced A-loads + 4 ds_reads + 8 independent
// MFMAs (258 cyc pipe). Halves chip A-traffic vs R11 (571->286 MB) and
// doubles per-wave ILP; R11 showed A-stream/TA co-limiting with MFMA.
// Registers: acc 128 + A 24 + B 32 + addr ~30 = ~215 <= 256 -> 2 waves/SIMD,
// matching the 64 KB LDS cap (2 blocks/CU). 4-wave block: min-waves/EU
// genuinely 1 (8-wave blocks force the 128 clamp -> R9/R10 spills).
__global__ __launch_bounds__(256, 1) void conv_mfma(
    const float* __restrict__ images,
    const unsigned char* __restrict__ W9Tf,
    const float* __restrict__ bias_dense,
    float* __restrict__ out)
{
    const int y0 = blockIdx.x * 2;
    const int b = blockIdx.y;
    const int t = threadIdx.x;
    const int w = t >> 6;             // 0..3
    const int l = t & 63;
    const int lm = l & 31;            // m-row / n-col within frag
    const int lhi = l >> 5;           // k-half

    __shared__ unsigned char lds[4 * LDSROW];   // 65536 B

    const float* __restrict__ imgb = images + (size_t)b * (IC * RR * CCOLS);

    // ---- stage 4 image rows, fp32 -> bf16, [x][c] with XOR swizzle ----
    // 256 threads: thread t stages x = t&63, 4 channel-octets per row.
    {
        const int xs = t & 63;
        const int og = t >> 6;              // 0..3
        const int swz = (xs & 7) << 4;
        #pragma unroll
        for (int krow = 0; krow < 4; ++krow) {
            #pragma unroll
            for (int h = 0; h < 4; ++h) {
                const int c0 = (og + 4 * h) * 8;    // octet base channel
                const float* __restrict__ p =
                    imgb + (size_t)c0 * (RR * CCOLS) + (y0 + krow) * CCOLS + xs;
                unsigned v0, v1, v2, v3;
                v0 = (unsigned)f2bf(p[0])              | ((unsigned)f2bf(p[RR * CCOLS])     << 16);
                v1 = (unsigned)f2bf(p[2 * RR * CCOLS]) | ((unsigned)f2bf(p[3 * RR * CCOLS]) << 16);
                v2 = (unsigned)f2bf(p[4 * RR * CCOLS]) | ((unsigned)f2bf(p[5 * RR * CCOLS]) << 16);
                v3 = (unsigned)f2bf(p[6 * RR * CCOLS]) | ((unsigned)f2bf(p[7 * RR * CCOLS]) << 16);
                *(uint4*)(lds + krow * LDSROW + xs * 256 + ((c0 * 2) ^ swz)) =
                    make_uint4(v0, v1, v2, v3);
            }
        }
    }

    // lane's coalesced A bases for the wave's two oc-groups
    const unsigned char* __restrict__ pA0 = W9Tf + (2 * w + 0) * 1024 + l * 16;
    const unsigned char* __restrict__ pA1 = W9Tf + (2 * w + 1) * 1024 + l * 16;

    // prologue: prefetch A chunks 0..2 for both groups (global, no hazard)
    bf16x8 a0C  = *(const bf16x8*)(pA0);
    bf16x8 a1C  = *(const bf16x8*)(pA1);
    bf16x8 a0N1 = *(const bf16x8*)(pA0 + CHUNK_STRIDE);
    bf16x8 a1N1 = *(const bf16x8*)(pA1 + CHUNK_STRIDE);
    bf16x8 a0N2 = *(const bf16x8*)(pA0 + 2 * CHUNK_STRIDE);
    bf16x8 a1N2 = *(const bf16x8*)(pA1 + 2 * CHUNK_STRIDE);

    __syncthreads();

    // B reader for chunk idx: fragments for both y-rows x both n-tiles
    auto readB = [&](int idx, bf16x8& b00, bf16x8& b01, bf16x8& b10, bf16x8& b11) {
        const int kp = idx >> 3, ck = idx & 7;
        const int ky = kp / 3, kx = kp % 3;
        const int x0 = lm + kx;                      // <= 33, in-bounds
        int x1 = 32 + lm + kx;
        x1 = x1 > 63 ? 63 : x1;   // pad lanes: dup col 63 (output discarded)
        const int pb0 = (x0 * 256 + ((lhi * 16) ^ ((x0 & 7) << 4))) ^ (ck * 32);
        const int pb1 = (x1 * 256 + ((lhi * 16) ^ ((x1 & 7) << 4))) ^ (ck * 32);
        const unsigned char* __restrict__ row0 = lds + (ky + 0) * LDSROW;
        const unsigned char* __restrict__ row1 = lds + (ky + 1) * LDSROW;
        b00 = *(const bf16x8*)(row0 + pb0);
        b01 = *(const bf16x8*)(row0 + pb1);
        b10 = *(const bf16x8*)(row1 + pb0);
        b11 = *(const bf16x8*)(row1 + pb1);
    };

    // named accumulators c<m><y><n> (static indexing -> no scratch; rule #20)
    f32x16 c000 = {}, c001 = {}, c010 = {}, c011 = {};
    f32x16 c100 = {}, c101 = {}, c110 = {}, c111 = {};
    bf16x8 b00c, b01c, b10c, b11c;
    readB(0, b00c, b01c, b10c, b11c);

    #pragma unroll
    for (int idx = 0; idx < 72; ++idx) {
        // prefetch A chunk idx+3 for both groups (coalesced 1 KB loads)
        bf16x8 a0N3, a1N3;
        if (idx + 3 < 72) {
            a0N3 = *(const bf16x8*)(pA0 + (size_t)(idx + 3) * CHUNK_STRIDE);
            a1N3 = *(const bf16x8*)(pA1 + (size_t)(idx + 3) * CHUNK_STRIDE);
        }
        // prefetch B chunk idx+1 (4x ds_read_b128, covered by MFMAs below)
        bf16x8 b00n, b01n, b10n, b11n;
        if (idx + 1 < 72) readB(idx + 1, b00n, b01n, b10n, b11n);

        c000 = __builtin_amdgcn_mfma_f32_32x32x16_bf16(a0C, b00c, c000, 0, 0, 0);
        c100 = __builtin_amdgcn_mfma_f32_32x32x16_bf16(a1C, b00c, c100, 0, 0, 0);
        c001 = __builtin_amdgcn_mfma_f32_32x32x16_bf16(a0C, b01c, c001, 0, 0, 0);
        c101 = __builtin_amdgcn_mfma_f32_32x32x16_bf16(a1C, b01c, c101, 0, 0, 0);
        c010 = __builtin_amdgcn_mfma_f32_32x32x16_bf16(a0C, b10c, c010, 0, 0, 0);
        c110 = __builtin_amdgcn_mfma_f32_32x32x16_bf16(a1C, b10c, c110, 0, 0, 0);
        c011 = __builtin_amdgcn_mfma_f32_32x32x16_bf16(a0C, b11c, c011, 0, 0, 0);
        c111 = __builtin_amdgcn_mfma_f32_32x32x16_bf16(a1C, b11c, c111, 0, 0, 0);

        a0C = a0N1; a0N1 = a0N2; a0N2 = a0N3;    // SSA-renamed, no copies
        a1C = a1N1; a1N1 = a1N2; a1N2 = a1N3;
        if (idx + 1 < 72) { b00c = b00n; b01c = b01n; b10c = b10n; b11c = b11n; }
    }

    // ---- epilogue: bias + store ----
    // C/D 32x32: col = lane&31, row = (reg&3) + 8*(reg>>2) + 4*(lane>>5)
    #pragma unroll
    for (int m = 0; m < 2; ++m) {
        const int ocw = (2 * w + m) * 32;
        const f32x16 d00 = m ? c100 : c000;   // [y0][n0]
        const f32x16 d01 = m ? c101 : c001;   // [y0][n1]
        const f32x16 d10 = m ? c110 : c010;   // [y1][n0]
        const f32x16 d11 = m ? c111 : c011;   // [y1][n1]
        #pragma unroll
        for (int r = 0; r < 16; ++r) {
            const int oc = ocw + (r & 3) + 8 * (r >> 2) + 4 * lhi;
            const float bv = bias_dense[oc];
            const size_t ob0 = (((size_t)b * OC + oc) * HO + y0) * WO;
            out[ob0 + lm] = d00[r] + bv;             // x = lm < 62 always
            if (lm < 30)
                out[ob0 + 32 + lm] = d01[r] + bv;    // x = 32+lm, clip at 62
            const size_t ob1 = ob0 + WO;             // row y0+1
            out[ob1 + lm] = d10[r] + bv;
            if (lm < 30)
                out[ob1 + 32 + lm] = d11[r] + bv;
        }
    }
}

extern "C" void kernel_launch(void* const* d_in, const int* in_sizes, int n_in,
                              void* d_out, int out_size, void* d_ws, size_t ws_size,
                              hipStream_t stream) {
    const float* images             = (const float*)d_in[0];
    const float* weight_value       = (const float*)d_in[1];
    const int*   image_weight_index = (const int*)d_in[2];
    const int*   filter_lengths     = (const int*)d_in[3];
    const int*   start_points       = (const int*)d_in[4];
    const int*   bias_index         = (const int*)d_in[5];
    const float* bias_value         = (const float*)d_in[6];
    float* out = (float*)d_out;

    unsigned char* W9Tf = (unsigned char*)d_ws;
    float* bias_dense = (float*)((char*)d_ws + W9T_BYTES);

    hipMemsetAsync(d_ws, 0, W9T_BYTES, stream);
    prep_weights<<<OC, 256, 0, stream>>>(weight_value, image_weight_index,
                                         filter_lengths, start_points, W9Tf);
    bias_kernel<<<1, 256, 0, stream>>>(bias_index, bias_value, bias_dense,
                                       in_sizes[5]);

    dim3 grid(HO / 2, NB);
    conv_mfma<<<grid, 256, 0, stream>>>(images, W9Tf, bias_dense, out);
}

// Round 13
// 84.171 us; speedup vs baseline: 1.0006x; 1.0006x over previous
//
#include <hip/hip_runtime.h>

#define IC 128
#define OC 256
#define RR 64
#define CCOLS 64
#define HO 62
#define WO 62
#define NB 16

// Fragment-major dense bf16 weights:
//   W9Tf[chunk][g][lane][elem], chunk = kp*8+ck (72), g = oc>>5 (8 groups),
//   lane = (oc&31) + 32*khalf (64), elem = c&7 (8 bf16 = 16 B).
// A wave's A-fragment load for one chunk/group is base + lane*16: 1 KB
// contiguous (coalesced; the R8 win).
#define W9T_BYTES (9 * OC * IC * 2)   // 589824
#define CHUNK_STRIDE 8192             // 8 ocgroups * 64 lanes * 16 B
#define LDSROW 16384                  // one image row: 64 x * 256 B

typedef __bf16 bf16x8 __attribute__((ext_vector_type(8)));
typedef float f32x16 __attribute__((ext_vector_type(16)));

__device__ __forceinline__ unsigned short f2bf(float f) {
    unsigned u = __builtin_bit_cast(unsigned, f);
    u += 0x7FFFu + ((u >> 16) & 1u);   // round-to-nearest-even
    return (unsigned short)(u >> 16);
}

__global__ void prep_weights(const float* __restrict__ wv,
                             const int* __restrict__ iwi,
                             const int* __restrict__ flen,
                             const int* __restrict__ sp,
                             unsigned char* __restrict__ W9Tf) {
    const int oc = blockIdx.x;
    const int s = sp[oc];
    const int n = flen[oc];
    const int g = oc >> 5;
    for (int t = threadIdx.x; t < n; t += blockDim.x) {
        const int ix = iwi[s + t];          // c*4096 + ky*64 + kx
        const int c = ix >> 12;
        const int rem = ix & 4095;
        const int ky = rem >> 6, kx = rem & 63;
        const int kp = ky * 3 + kx;
        const int ck = c >> 4;
        const int khalf = (c >> 3) & 1;
        const int lane = (oc & 31) + (khalf << 5);
        const size_t off = (size_t)(kp * 8 + ck) * CHUNK_STRIDE +
                           g * 1024 + lane * 16 + (c & 7) * 2;
        *(unsigned short*)(W9Tf + off) = f2bf(wv[s + t]);
    }
}

__global__ void bias_kernel(const int* __restrict__ bias_index,
                            const float* __restrict__ bias_value,
                            float* __restrict__ bias_dense, int nbias) {
    int t = threadIdx.x;
    if (t < OC) bias_dense[t] = 0.f;
    __syncthreads();
    if (t < nbias) atomicAdd(&bias_dense[bias_index[t]], bias_value[t]);
}

// One K-chunk step, IDX a literal constant. All control flow is
// `if constexpr`; all chunk-dependent offsets are compile-time constants.
// R12's `#pragma unroll for(idx<72)` was NOT actually unrolled (evidence:
// ~80 VALU instrs/iter = runtime /3 %3 + guards; ~300-400 cyc serial stall
// per memory op = conservative waitcnts at branch boundaries).
#define KSTEP(IDX)                                                            \
  {                                                                           \
    bf16x8 a0N3, a1N3;                                                        \
    if constexpr ((IDX) + 3 < 72) {                                           \
      a0N3 = *(const bf16x8*)(pA0 + (size_t)((IDX) + 3) * CHUNK_STRIDE);      \
      a1N3 = *(const bf16x8*)(pA1 + (size_t)((IDX) + 3) * CHUNK_STRIDE);      \
    }                                                                         \
    bf16x8 b00n, b01n, b10n, b11n;                                            \
    if constexpr ((IDX) + 1 < 72) {                                           \
      constexpr int np_ = ((IDX) + 1) >> 3, nc_ = ((IDX) + 1) & 7;            \
      constexpr int nky_ = np_ / 3, nkx_ = np_ % 3;                           \
      const int x0_ = lm + nkx_;                                              \
      int x1_ = 32 + lm + nkx_;                                               \
      x1_ = x1_ > 63 ? 63 : x1_;                                              \
      const int pb0_ = (x0_ * 256 + (lhi16 ^ ((x0_ & 7) << 4))) ^ (nc_ * 32); \
      const int pb1_ = (x1_ * 256 + (lhi16 ^ ((x1_ & 7) << 4))) ^ (nc_ * 32); \
      const unsigned char* r0_ = lds + (nky_ + 0) * LDSROW;                   \
      const unsigned char* r1_ = lds + (nky_ + 1) * LDSROW;                   \
      b00n = *(const bf16x8*)(r0_ + pb0_);                                    \
      b01n = *(const bf16x8*)(r0_ + pb1_);                                    \
      b10n = *(const bf16x8*)(r1_ + pb0_);                                    \
      b11n = *(const bf16x8*)(r1_ + pb1_);                                    \
    }                                                                         \
    c000 = __builtin_amdgcn_mfma_f32_32x32x16_bf16(a0C, b00c, c000, 0, 0, 0); \
    c100 = __builtin_amdgcn_mfma_f32_32x32x16_bf16(a1C, b00c, c100, 0, 0, 0); \
    c001 = __builtin_amdgcn_mfma_f32_32x32x16_bf16(a0C, b01c, c001, 0, 0, 0); \
    c101 = __builtin_amdgcn_mfma_f32_32x32x16_bf16(a1C, b01c, c101, 0, 0, 0); \
    c010 = __builtin_amdgcn_mfma_f32_32x32x16_bf16(a0C, b10c, c010, 0, 0, 0); \
    c110 = __builtin_amdgcn_mfma_f32_32x32x16_bf16(a1C, b10c, c110, 0, 0, 0); \
    c011 = __builtin_amdgcn_mfma_f32_32x32x16_bf16(a0C, b11c, c011, 0, 0, 0); \
    c111 = __builtin_amdgcn_mfma_f32_32x32x16_bf16(a1C, b11c, c111, 0, 0, 0); \
    a0C = a0N1; a1C = a1N1;                                                   \
    a0N1 = a0N2; a1N1 = a1N2;                                                 \
    if constexpr ((IDX) + 3 < 72) { a0N2 = a0N3; a1N2 = a1N3; }               \
    if constexpr ((IDX) + 1 < 72) {                                           \
      b00c = b00n; b01c = b01n; b10c = b10n; b11c = b11n;                     \
    }                                                                         \
  }

#define K8(B) KSTEP(B) KSTEP((B)+1) KSTEP((B)+2) KSTEP((B)+3) \
              KSTEP((B)+4) KSTEP((B)+5) KSTEP((B)+6) KSTEP((B)+7)

// Block = (b, 2 output rows) x all 256 oc. 256 threads = 4 waves.
// Wave w: 64 oc (groups 2w, 2w+1) x 64 x (2 n-tiles) x 2 y-rows:
// per K-chunk step = 2 coalesced A-loads + 4 ds_reads + 8 independent MFMAs.
// LDS rows y0..y0+3, x-major bf16, XOR-swizzled, 64 KB (2 blocks/CU).
__global__ __launch_bounds__(256, 1) void conv_mfma(
    const float* __restrict__ images,
    const unsigned char* __restrict__ W9Tf,
    const float* __restrict__ bias_dense,
    float* __restrict__ out)
{
    const int y0 = blockIdx.x * 2;
    const int b = blockIdx.y;
    const int t = threadIdx.x;
    const int w = t >> 6;             // 0..3
    const int l = t & 63;
    const int lm = l & 31;            // m-row / n-col within frag
    const int lhi16 = (l >> 5) * 16;  // k-half byte offset

    __shared__ unsigned char lds[4 * LDSROW];   // 65536 B

    const float* __restrict__ imgb = images + (size_t)b * (IC * RR * CCOLS);

    // ---- stage 4 image rows, fp32 -> bf16, [x][c] with XOR swizzle ----
    {
        const int xs = t & 63;
        const int og = t >> 6;              // 0..3
        const int swz = (xs & 7) << 4;
        #pragma unroll
        for (int krow = 0; krow < 4; ++krow) {
            #pragma unroll
            for (int h = 0; h < 4; ++h) {
                const int c0 = (og + 4 * h) * 8;    // octet base channel
                const float* __restrict__ p =
                    imgb + (size_t)c0 * (RR * CCOLS) + (y0 + krow) * CCOLS + xs;
                unsigned v0, v1, v2, v3;
                v0 = (unsigned)f2bf(p[0])              | ((unsigned)f2bf(p[RR * CCOLS])     << 16);
                v1 = (unsigned)f2bf(p[2 * RR * CCOLS]) | ((unsigned)f2bf(p[3 * RR * CCOLS]) << 16);
                v2 = (unsigned)f2bf(p[4 * RR * CCOLS]) | ((unsigned)f2bf(p[5 * RR * CCOLS]) << 16);
                v3 = (unsigned)f2bf(p[6 * RR * CCOLS]) | ((unsigned)f2bf(p[7 * RR * CCOLS]) << 16);
                *(uint4*)(lds + krow * LDSROW + xs * 256 + ((c0 * 2) ^ swz)) =
                    make_uint4(v0, v1, v2, v3);
            }
        }
    }

    // lane's coalesced A bases for the wave's two oc-groups
    const unsigned char* __restrict__ pA0 = W9Tf + (2 * w + 0) * 1024 + l * 16;
    const unsigned char* __restrict__ pA1 = W9Tf + (2 * w + 1) * 1024 + l * 16;

    // prologue: prefetch A chunks 0..2 for both groups (global, no hazard)
    bf16x8 a0C  = *(const bf16x8*)(pA0);
    bf16x8 a1C  = *(const bf16x8*)(pA1);
    bf16x8 a0N1 = *(const bf16x8*)(pA0 + CHUNK_STRIDE);
    bf16x8 a1N1 = *(const bf16x8*)(pA1 + CHUNK_STRIDE);
    bf16x8 a0N2 = *(const bf16x8*)(pA0 + 2 * CHUNK_STRIDE);
    bf16x8 a1N2 = *(const bf16x8*)(pA1 + 2 * CHUNK_STRIDE);

    __syncthreads();

    // named accumulators c<m><y><n> (static indexing -> no scratch; rule #20)
    f32x16 c000 = {}, c001 = {}, c010 = {}, c011 = {};
    f32x16 c100 = {}, c101 = {}, c110 = {}, c111 = {};

    // initial B read: chunk 0 (kp=0 -> ky=0, kx=0, ck=0)
    bf16x8 b00c, b01c, b10c, b11c;
    {
        const int x0_ = lm;
        int x1_ = 32 + lm;
        x1_ = x1_ > 63 ? 63 : x1_;
        const int pb0_ = x0_ * 256 + (lhi16 ^ ((x0_ & 7) << 4));
        const int pb1_ = x1_ * 256 + (lhi16 ^ ((x1_ & 7) << 4));
        b00c = *(const bf16x8*)(lds + pb0_);
        b01c = *(const bf16x8*)(lds + pb1_);
        b10c = *(const bf16x8*)(lds + LDSROW + pb0_);
        b11c = *(const bf16x8*)(lds + LDSROW + pb1_);
    }

    // 72 straight-line K-steps (literal indices, zero runtime branches)
    K8(0) K8(8) K8(16) K8(24) K8(32) K8(40) K8(48) K8(56) K8(64)

    // ---- epilogue: bias + store ----
    // C/D 32x32: col = lane&31, row = (reg&3) + 8*(reg>>2) + 4*(lane>>5)
    #pragma unroll
    for (int m = 0; m < 2; ++m) {
        const int ocw = (2 * w + m) * 32;
        const f32x16 d00 = m ? c100 : c000;   // [y0][n0]
        const f32x16 d01 = m ? c101 : c001;   // [y0][n1]
        const f32x16 d10 = m ? c110 : c010;   // [y1][n0]
        const f32x16 d11 = m ? c111 : c011;   // [y1][n1]
        #pragma unroll
        for (int r = 0; r < 16; ++r) {
            const int oc = ocw + (r & 3) + 8 * (r >> 2) + (lhi16 >> 2);
            const float bv = bias_dense[oc];
            const size_t ob0 = (((size_t)b * OC + oc) * HO + y0) * WO;
            out[ob0 + lm] = d00[r] + bv;             // x = lm < 62 always
            if (lm < 30)
                out[ob0 + 32 + lm] = d01[r] + bv;    // x = 32+lm, clip at 62
            const size_t ob1 = ob0 + WO;             // row y0+1
            out[ob1 + lm] = d10[r] + bv;
            if (lm < 30)
                out[ob1 + 32 + lm] = d11[r] + bv;
        }
    }
}

extern "C" void kernel_launch(void* const* d_in, const int* in_sizes, int n_in,
                              void* d_out, int out_size, void* d_ws, size_t ws_size,
                              hipStream_t stream) {
    const float* images             = (const float*)d_in[0];
    const float* weight_value       = (const float*)d_in[1];
    const int*   image_weight_index = (const int*)d_in[2];
    const int*   filter_lengths     = (const int*)d_in[3];
    const int*   start_points       = (const int*)d_in[4];
    const int*   bias_index         = (const int*)d_in[5];
    const float* bias_value         = (const float*)d_in[6];
    float* out = (float*)d_out;

    unsigned char* W9Tf = (unsigned char*)d_ws;
    float* bias_dense = (float*)((char*)d_ws + W9T_BYTES);

    hipMemsetAsync(d_ws, 0, W9T_BYTES, stream);
    prep_weights<<<OC, 256, 0, stream>>>(weight_value, image_weight_index,
                                         filter_lengths, start_points, W9Tf);
    bias_kernel<<<1, 256, 0, stream>>>(bias_index, bias_value, bias_dense,
                                       in_sizes[5]);

    dim3 grid(HO / 2, NB);
    conv_mfma<<<grid, 256, 0, stream>>>(images, W9Tf, bias_dense, out);
}

// Round 14
// 70.777 us; speedup vs baseline: 1.1899x; 1.1892x over previous
//
#include <hip/hip_runtime.h>

#define IC 128
#define OC 256
#define RR 64
#define CCOLS 64
#define HO 62
#define WO 62
#define NB 16

// Fragment-major dense bf16 weights:
//   W9Tf[chunk][g][lane][elem], chunk = kp*8+ck (72), g = oc>>5 (8 groups),
//   lane = (oc&31) + 32*khalf (64), elem = c&7 (8 bf16 = 16 B).
// A wave's A-fragment load for one chunk/group is base + lane*16: 1 KB
// contiguous (coalesced; the R8 win).
#define W9T_BYTES (9 * OC * IC * 2)   // 589824
#define CHUNK_STRIDE 8192             // 8 ocgroups * 64 lanes * 16 B
#define LDSROW 16384                  // one image row: 64 x * 256 B

typedef __bf16 bf16x8 __attribute__((ext_vector_type(8)));
typedef float f32x16 __attribute__((ext_vector_type(16)));

__device__ __forceinline__ unsigned short f2bf(float f) {
    unsigned u = __builtin_bit_cast(unsigned, f);
    u += 0x7FFFu + ((u >> 16) & 1u);   // round-to-nearest-even
    return (unsigned short)(u >> 16);
}

// prep: blocks 0..OC-1 scatter weights; block OC densifies the bias.
__global__ void prep_weights(const float* __restrict__ wv,
                             const int* __restrict__ iwi,
                             const int* __restrict__ flen,
                             const int* __restrict__ sp,
                             unsigned char* __restrict__ W9Tf,
                             const int* __restrict__ bias_index,
                             const float* __restrict__ bias_value,
                             float* __restrict__ bias_dense, int nbias) {
    if (blockIdx.x == OC) {
        int t = threadIdx.x;
        if (t < OC) bias_dense[t] = 0.f;
        __syncthreads();
        if (t < nbias) atomicAdd(&bias_dense[bias_index[t]], bias_value[t]);
        return;
    }
    const int oc = blockIdx.x;
    const int s = sp[oc];
    const int n = flen[oc];
    const int g = oc >> 5;
    for (int t = threadIdx.x; t < n; t += blockDim.x) {
        const int ix = iwi[s + t];          // c*4096 + ky*64 + kx
        const int c = ix >> 12;
        const int rem = ix & 4095;
        const int ky = rem >> 6, kx = rem & 63;
        const int kp = ky * 3 + kx;
        const int ck = c >> 4;
        const int khalf = (c >> 3) & 1;
        const int lane = (oc & 31) + (khalf << 5);
        const size_t off = (size_t)(kp * 8 + ck) * CHUNK_STRIDE +
                           g * 1024 + lane * 16 + (c & 7) * 2;
        *(unsigned short*)(W9Tf + off) = f2bf(wv[s + t]);
    }
}

// Block = one output row (b, y) x all 256 oc. 512 threads = 8 waves.
// Wave w: 32 oc (one 32x32 m-frag) x 64 x (2 n-tiles). R8 structure (the
// 64us champion: best TLP point at 16 waves/CU) + deeper prefetch:
// A 4-deep (global L2 latency) and B 2-deep (LDS latency), total ~108
// unified regs/wave -> still 4 waves/SIMD (512-reg pool), occupancy kept.
__global__ __launch_bounds__(512, 2) void conv_mfma(
    const float* __restrict__ images,
    const unsigned char* __restrict__ W9Tf,
    const float* __restrict__ bias_dense,
    float* __restrict__ out)
{
    const int y = blockIdx.x;
    const int b = blockIdx.y;
    const int t = threadIdx.x;
    const int w = t >> 6;
    const int l = t & 63;
    const int lm = l & 31;            // m-row / n-col within frag
    const int lhi16 = (l >> 5) * 16;  // k-half byte offset

    __shared__ unsigned char lds[3 * LDSROW];   // 49152 B

    const float* __restrict__ imgb = images + (size_t)b * (IC * RR * CCOLS);

    // ---- stage 3 image rows, fp32 -> bf16, [x][c] with XOR swizzle ----
    {
        const int xs = t & 63;
        const int oct = t >> 6;             // 0..7
        const int swz = (xs & 7) << 4;
        #pragma unroll
        for (int krow = 0; krow < 3; ++krow) {
            #pragma unroll
            for (int h = 0; h < 2; ++h) {
                const int c0 = (oct + 8 * h) * 8;   // octet base channel
                const float* __restrict__ p =
                    imgb + (size_t)c0 * (RR * CCOLS) + (y + krow) * CCOLS + xs;
                unsigned v0, v1, v2, v3;
                v0 = (unsigned)f2bf(p[0])              | ((unsigned)f2bf(p[RR * CCOLS])     << 16);
                v1 = (unsigned)f2bf(p[2 * RR * CCOLS]) | ((unsigned)f2bf(p[3 * RR * CCOLS]) << 16);
                v2 = (unsigned)f2bf(p[4 * RR * CCOLS]) | ((unsigned)f2bf(p[5 * RR * CCOLS]) << 16);
                v3 = (unsigned)f2bf(p[6 * RR * CCOLS]) | ((unsigned)f2bf(p[7 * RR * CCOLS]) << 16);
                *(uint4*)(lds + krow * LDSROW + xs * 256 + ((c0 * 2) ^ swz)) =
                    make_uint4(v0, v1, v2, v3);
            }
        }
    }

    // lane's coalesced A base
    const unsigned char* __restrict__ pA = W9Tf + w * 1024 + l * 16;

    // prologue: prefetch A chunks 0..3 (global only, no LDS hazard)
    bf16x8 aC  = *(const bf16x8*)(pA);
    bf16x8 aN1 = *(const bf16x8*)(pA + CHUNK_STRIDE);
    bf16x8 aN2 = *(const bf16x8*)(pA + 2 * CHUNK_STRIDE);
    bf16x8 aN3 = *(const bf16x8*)(pA + 3 * CHUNK_STRIDE);

    __syncthreads();

    // B reader for chunk idx (compile-time ky/kx/ck under full unroll)
    auto readB = [&](int idx, bf16x8& b0, bf16x8& b1) {
        const int kp = idx >> 3, ck = idx & 7;
        const int ky = kp / 3, kx = kp % 3;
        const int x0 = lm + kx;                      // <= 33, in-bounds
        int x1 = 32 + lm + kx;
        x1 = x1 > 63 ? 63 : x1;   // pad lanes: dup col 63 (output discarded)
        const unsigned char* __restrict__ row = lds + ky * LDSROW;
        const int pb0 = (x0 * 256 + (lhi16 ^ ((x0 & 7) << 4))) ^ (ck * 32);
        const int pb1 = (x1 * 256 + (lhi16 ^ ((x1 & 7) << 4))) ^ (ck * 32);
        b0 = *(const bf16x8*)(row + pb0);
        b1 = *(const bf16x8*)(row + pb1);
    };

    f32x16 acc0 = {}, acc1 = {};
    bf16x8 b0c, b1c, b0n1, b1n1;
    readB(0, b0c, b1c);
    readB(1, b0n1, b1n1);

    #pragma unroll
    for (int idx = 0; idx < 72; ++idx) {
        // prefetch A chunk idx+4 (coalesced 1 KB global load)
        bf16x8 aN4;
        if (idx + 4 < 72)
            aN4 = *(const bf16x8*)(pA + (size_t)(idx + 4) * CHUNK_STRIDE);
        // prefetch B chunk idx+2 (2x ds_read_b128, 2 iters of cover)
        bf16x8 b0n2, b1n2;
        if (idx + 2 < 72) readB(idx + 2, b0n2, b1n2);

        acc0 = __builtin_amdgcn_mfma_f32_32x32x16_bf16(aC, b0c, acc0, 0, 0, 0);
        acc1 = __builtin_amdgcn_mfma_f32_32x32x16_bf16(aC, b1c, acc1, 0, 0, 0);

        aC = aN1; aN1 = aN2; aN2 = aN3;              // SSA-renamed, no copies
        if (idx + 4 < 72) aN3 = aN4;
        b0c = b0n1; b1c = b1n1;
        if (idx + 2 < 72) { b0n1 = b0n2; b1n1 = b1n2; }
    }

    // ---- epilogue: bias + store ----
    // C/D 32x32: col = lane&31, row = (reg&3) + 8*(reg>>2) + 4*(lane>>5)
    const int ocw = 32 * w;
    #pragma unroll
    for (int r = 0; r < 16; ++r) {
        const int oc = ocw + (r & 3) + 8 * (r >> 2) + (lhi16 >> 2);
        const float bv = bias_dense[oc];
        const size_t ob = (((size_t)b * OC + oc) * HO + y) * WO;
        out[ob + lm] = acc0[r] + bv;             // x = lm < 62 always
        if (lm < 30)
            out[ob + 32 + lm] = acc1[r] + bv;    // x = 32+lm, clip at 62
    }
}

extern "C" void kernel_launch(void* const* d_in, const int* in_sizes, int n_in,
                              void* d_out, int out_size, void* d_ws, size_t ws_size,
                              hipStream_t stream) {
    const float* images             = (const float*)d_in[0];
    const float* weight_value       = (const float*)d_in[1];
    const int*   image_weight_index = (const int*)d_in[2];
    const int*   filter_lengths     = (const int*)d_in[3];
    const int*   start_points       = (const int*)d_in[4];
    const int*   bias_index         = (const int*)d_in[5];
    const float* bias_value         = (const float*)d_in[6];
    float* out = (float*)d_out;

    unsigned char* W9Tf = (unsigned char*)d_ws;
    float* bias_dense = (float*)((char*)d_ws + W9T_BYTES);

    hipMemsetAsync(d_ws, 0, W9T_BYTES, stream);
    prep_weights<<<OC + 1, 256, 0, stream>>>(weight_value, image_weight_index,
                                             filter_lengths, start_points, W9Tf,
                                             bias_index, bias_value, bias_dense,
                                             in_sizes[5]);

    dim3 grid(HO, NB);
    conv_mfma<<<grid, 512, 0, stream>>>(images, W9Tf, bias_dense, out);
}